// Round 5
// baseline (263.726 us; speedup 1.0000x reference)
//
#include <hip/hip_runtime.h>

typedef __attribute__((ext_vector_type(8))) short bf16x8;
typedef __attribute__((ext_vector_type(4))) float f32x4;

#define HEADS 12
#define NN 512
#define BB 8
#define DIM 768
#define LDK 72    // BK=64 LDS row: 64 bf16 + 8 pad  (144B stride)
#define LDV 136   // 128 bf16 + 8 pad (272B stride)
#define OUT0_ELEMS ((size_t)BB*NN*DIM)

__device__ __forceinline__ ushort f2bf(float f) {
  union { float f; uint u; } v; v.f = f;
  uint r = v.u + 0x7fffu + ((v.u >> 16) & 1u);   // RNE
  return (ushort)(r >> 16);
}

// ---------- fused fp32 -> bf16 conversion for qkv_w, proj_w, x ----------
__global__ __launch_bounds__(256) void cvt3_kernel(
    const float* __restrict__ a, ushort* __restrict__ oa, int na8,
    const float* __restrict__ b, ushort* __restrict__ ob, int nb8,
    const float* __restrict__ c, ushort* __restrict__ oc, int nc8) {
  int i = blockIdx.x * 256 + threadIdx.x;
  const float* in; ushort* out;
  if (i < na8) { in = a; out = oa; }
  else if (i < na8 + nb8) { i -= na8; in = b; out = ob; }
  else { i -= na8 + nb8; if (i >= nc8) return; in = c; out = oc; }
  float4 x = ((const float4*)in)[i*2], y = ((const float4*)in)[i*2+1];
  uint4 o;
  o.x = f2bf(x.x) | ((uint)f2bf(x.y) << 16);
  o.y = f2bf(x.z) | ((uint)f2bf(x.w) << 16);
  o.z = f2bf(y.x) | ((uint)f2bf(y.y) << 16);
  o.w = f2bf(y.z) | ((uint)f2bf(y.w) << 16);
  ((uint4*)out)[i] = o;
}

// ---------- QKV GEMM (bf16 MFMA) + fused L2-normalize-square + V transpose ----------
__global__ __launch_bounds__(256) void qkv_gemm(
    const ushort* __restrict__ xb, const ushort* __restrict__ wb,
    ushort* __restrict__ q2b, ushort* __restrict__ k2b, ushort* __restrict__ vt)
{
  __shared__ ushort As[128 * LDK];
  __shared__ ushort Bs[128 * LDK];
  const int t = threadIdx.x, l = t & 63, w = t >> 6;
  const int bx = blockIdx.x, by = blockIdx.y;     // col tile (18), row tile (32)
  const int rowbase = by * 128, colbase = bx * 128;
  const int wr = w >> 1, wc = w & 1, lr = l & 15, lg = l >> 4;
  f32x4 acc[4][4] = {};

  for (int kc = 0; kc < DIM; kc += 64) {
    #pragma unroll
    for (int i = 0; i < 4; ++i) {
      int c = t + 256 * i;
      int r = c >> 3, k16 = c & 7;
      *(uint4*)(As + r * LDK + k16 * 8) =
          *(const uint4*)(xb + (size_t)(rowbase + r) * DIM + kc + k16 * 8);
      *(uint4*)(Bs + r * LDK + k16 * 8) =
          *(const uint4*)(wb + (size_t)(colbase + r) * DIM + kc + k16 * 8);
    }
    __syncthreads();
    #pragma unroll
    for (int ks = 0; ks < 2; ++ks) {
      bf16x8 af[4], bg[4];
      #pragma unroll
      for (int i = 0; i < 4; ++i)
        af[i] = *(const bf16x8*)(As + (wr*64 + i*16 + lr) * LDK + ks*32 + lg*8);
      #pragma unroll
      for (int j = 0; j < 4; ++j)
        bg[j] = *(const bf16x8*)(Bs + (wc*64 + j*16 + lr) * LDK + ks*32 + lg*8);
      #pragma unroll
      for (int i = 0; i < 4; ++i)
        #pragma unroll
        for (int j = 0; j < 4; ++j)
          acc[i][j] = __builtin_amdgcn_mfma_f32_16x16x32_bf16(af[i], bg[j], acc[i][j], 0, 0, 0);
    }
    __syncthreads();
  }

  const int gcol = colbase + wc * 64;             // wave = exactly one head (64 cols)
  const int sel = gcol / DIM;                     // 0=q 1=k 2=v
  const int h = (gcol % DIM) / 64;
  if (sel < 2) {
    ushort* dst = (sel == 0) ? q2b : k2b;
    #pragma unroll
    for (int i = 0; i < 4; ++i) {
      #pragma unroll
      for (int r = 0; r < 4; ++r) {
        float vj[4]; float s = 0.f;
        #pragma unroll
        for (int j = 0; j < 4; ++j) { vj[j] = acc[i][j][r]; s += vj[j] * vj[j]; }
        #pragma unroll
        for (int off = 1; off < 16; off <<= 1) s += __shfl_xor(s, off);
        float inv = 1.0f / s;
        int row = rowbase + wr*64 + i*16 + lg*4 + r;
        int b = row >> 9, n = row & 511;
        ushort* o = dst + (((size_t)(b * HEADS + h) * NN + n) << 6);
        #pragma unroll
        for (int j = 0; j < 4; ++j) o[j*16 + lr] = f2bf(vj[j] * vj[j] * inv);
      }
    }
  } else {
    #pragma unroll
    for (int i = 0; i < 4; ++i) {
      int row0 = rowbase + wr*64 + i*16 + lg*4;
      int b = row0 >> 9, n0 = row0 & 511;
      #pragma unroll
      for (int j = 0; j < 4; ++j) {
        int d = j*16 + lr;
        ushort4 pk;
        pk.x = f2bf(acc[i][j][0]); pk.y = f2bf(acc[i][j][1]);
        pk.z = f2bf(acc[i][j][2]); pk.w = f2bf(acc[i][j][3]);
        *(ushort4*)(vt + (((size_t)(b * HEADS + h) * 64 + d) << 9) + n0) = pk;
      }
    }
  }
}

// ---------- LN stats: recompute attn tiles via MFMA, accumulate sum/sumsq only ----------
__global__ __launch_bounds__(256) void stats_kernel(
    const ushort* __restrict__ q2b, const ushort* __restrict__ k2b,
    double* __restrict__ hsum)
{
  __shared__ ushort Qs[256 * LDK];
  __shared__ ushort Ks[128 * LDK];
  __shared__ float red[8];
  const int t = threadIdx.x, l = t & 63, w = t >> 6;
  const int rt = blockIdx.x, h = blockIdx.y, b = blockIdx.z;
  const size_t bh = (size_t)(b * HEADS + h);
  const int rowbase = rt * 256;
  const int lr = l & 15, lg = l >> 4;
  #pragma unroll
  for (int i = 0; i < 8; ++i) {
    int c = t + 256 * i;
    int r = c >> 3, k16 = c & 7;
    *(uint4*)(Qs + r * LDK + k16 * 8) =
        *(const uint4*)(q2b + (bh << 15) + ((size_t)(rowbase + r) << 6) + k16 * 8);
  }
  float s1 = 0.f, s2 = 0.f;
  for (int ct = 0; ct < 4; ++ct) {
    #pragma unroll
    for (int i = 0; i < 4; ++i) {
      int c = t + 256 * i;
      int r = c >> 3, k16 = c & 7;
      *(uint4*)(Ks + r * LDK + k16 * 8) =
          *(const uint4*)(k2b + (bh << 15) + ((size_t)(ct*128 + r) << 6) + k16 * 8);
    }
    __syncthreads();
    bf16x8 af[4][2];
    #pragma unroll
    for (int i = 0; i < 4; ++i)
      #pragma unroll
      for (int ks = 0; ks < 2; ++ks)
        af[i][ks] = *(const bf16x8*)(Qs + (w*64 + i*16 + lr) * LDK + ks*32 + lg*8);
    #pragma unroll
    for (int j = 0; j < 8; ++j) {
      bf16x8 b0 = *(const bf16x8*)(Ks + (j*16 + lr) * LDK + lg*8);
      bf16x8 b1 = *(const bf16x8*)(Ks + (j*16 + lr) * LDK + 32 + lg*8);
      #pragma unroll
      for (int i = 0; i < 4; ++i) {
        f32x4 a = {};
        a = __builtin_amdgcn_mfma_f32_16x16x32_bf16(af[i][0], b0, a, 0, 0, 0);
        a = __builtin_amdgcn_mfma_f32_16x16x32_bf16(af[i][1], b1, a, 0, 0, 0);
        #pragma unroll
        for (int r = 0; r < 4; ++r) { s1 += a[r]; s2 += a[r]*a[r]; }
      }
    }
    __syncthreads();
  }
  #pragma unroll
  for (int off = 1; off < 64; off <<= 1) { s1 += __shfl_xor(s1, off); s2 += __shfl_xor(s2, off); }
  if (l == 0) { red[w] = s1; red[4 + w] = s2; }
  __syncthreads();
  if (t == 0) {
    double d1 = (double)red[0] + red[1] + red[2] + red[3];
    double d2 = (double)red[4] + red[5] + red[6] + red[7];
    atomicAdd(&hsum[b * 2], d1);
    atomicAdd(&hsum[b * 2 + 1], d2);
  }
}

// ---------- recompute attn strip (swapped operands: D[m][n]), LN with float4
// ---------- loads/stores, pack P via cvt_pk into swizzled LDS, PV -> obh ----------
__global__ __launch_bounds__(256) void norm_pv(
    const ushort* __restrict__ q2b, const ushort* __restrict__ k2b,
    const ushort* __restrict__ vt,
    const float* __restrict__ lnw, const float* __restrict__ lnb,
    const double* __restrict__ hsum,
    float* __restrict__ attn, ushort* __restrict__ obh)
{
  __shared__ ushort Qs[64 * LDK];    // 9.2 KB  persistent Q2 tile (64 n x 64 k)
  __shared__ ushort Ks[128 * LDK];   // 18.4 KB streamed K2 tile (128 m x 64 k)
  __shared__ ushort Vs[64 * LDV];    // 17.4 KB streamed Vt tile (64 d x 128 m)
  __shared__ ushort Pb[64 * 128];    // 16 KB   P bf16 (64 n x 128 m), XOR-swizzled 16B chunks
  const int t = threadIdx.x, l = t & 63, w = t >> 6;
  const int rt = blockIdx.x, h = blockIdx.y, b = blockIdx.z;
  const size_t bh = (size_t)(b * HEADS + h);
  const int rowbase = rt * 64;
  const int lr = l & 15, lg = l >> 4;
  const double cnt = (double)HEADS * NN * NN;
  double mu = hsum[b * 2] / cnt;
  double var = hsum[b * 2 + 1] / cnt - mu * mu;
  const float mean = (float)mu;
  const float istd = (float)(1.0 / sqrt(var + 1e-5));

  #pragma unroll
  for (int i = 0; i < 2; ++i) {
    int c = t + 256 * i;
    int r = c >> 3, k16 = c & 7;
    *(uint4*)(Qs + r * LDK + k16 * 8) =
        *(const uint4*)(q2b + (bh << 15) + ((size_t)(rowbase + r) << 6) + k16 * 8);
  }
  __syncthreads();
  // persistent Q fragments (B-operand of S): rows = n
  bf16x8 qf[4][2];
  #pragma unroll
  for (int j = 0; j < 4; ++j)
    #pragma unroll
    for (int ks = 0; ks < 2; ++ks)
      qf[j][ks] = *(const bf16x8*)(Qs + (j*16 + lr) * LDK + ks*32 + lg*8);

  f32x4 opv[4] = {};

  for (int ct = 0; ct < 4; ++ct) {
    #pragma unroll
    for (int i = 0; i < 4; ++i) {
      int c = t + 256 * i;
      int r = c >> 3, k16 = c & 7;
      *(uint4*)(Ks + r * LDK + k16 * 8) =
          *(const uint4*)(k2b + (bh << 15) + ((size_t)(ct*128 + r) << 6) + k16 * 8);
    }
    #pragma unroll
    for (int i = 0; i < 4; ++i) {
      int c = t + 256 * i;
      int r = c >> 4, k16 = c & 15;
      *(uint4*)(Vs + r * LDV + k16 * 8) =
          *(const uint4*)(vt + (bh << 15) + ((size_t)r << 9) + ct*128 + k16 * 8);
    }
    __syncthreads();
    // S^T = K2_tile @ Q2_tile^T: D[m][n]; wave w owns m-local w*32..w*32+31.
    // Lane's 4 acc regs = 4 consecutive m at fixed n -> float4 LN + row-quad stores.
    #pragma unroll
    for (int i = 0; i < 2; ++i) {
      bf16x8 a0 = *(const bf16x8*)(Ks + (w*32 + i*16 + lr) * LDK + lg*8);
      bf16x8 a1 = *(const bf16x8*)(Ks + (w*32 + i*16 + lr) * LDK + 32 + lg*8);
      const int mloc = w*32 + i*16 + lg*4;         // local m base (quad)
      const int m0 = ct*128 + mloc;                // global m base
      const int cch = mloc >> 3;                   // 16B-chunk index (4-bit)
      #pragma unroll
      for (int j = 0; j < 4; ++j) {
        f32x4 a = {};
        a = __builtin_amdgcn_mfma_f32_16x16x32_bf16(a0, qf[j][0], a, 0, 0, 0);
        a = __builtin_amdgcn_mfma_f32_16x16x32_bf16(a1, qf[j][1], a, 0, 0, 0);
        const int n = j*16 + lr;                   // local n
        const size_t rowoff = ((size_t)h * NN + rowbase + n) * NN + m0;
        const float4 lw4 = *(const float4*)(lnw + rowoff);
        const float4 lb4 = *(const float4*)(lnb + rowoff);
        f32x4 v;
        v[0] = (a[0] - mean) * istd * lw4.x + lb4.x;
        v[1] = (a[1] - mean) * istd * lw4.y + lb4.y;
        v[2] = (a[2] - mean) * istd * lw4.z + lb4.z;
        v[3] = (a[3] - mean) * istd * lw4.w + lb4.w;
        __builtin_nontemporal_store(v,
            (f32x4*)(attn + ((bh << 9) + rowbase + n) * NN + m0));
        uint pk01, pk23;
        asm("v_cvt_pk_bf16_f32 %0, %1, %2" : "=v"(pk01) : "v"(v[0]), "v"(v[1]));
        asm("v_cvt_pk_bf16_f32 %0, %1, %2" : "=v"(pk23) : "v"(v[2]), "v"(v[3]));
        const int pch = (cch & 8) | ((cch & 7) ^ (n & 7));
        uint2 pk = { pk01, pk23 };
        *(uint2*)(Pb + n*128 + pch*8 + (lg & 1)*4) = pk;
      }
    }
    __syncthreads();
    // PV: out[n][d] += sum_m P[n][m] * Vt[d][m]; wave w owns n-local w*16..w*16+15
    #pragma unroll
    for (int ks = 0; ks < 4; ++ks) {
      const int cc = ks*4 + lg;
      const int nl = w*16 + lr;
      const int pch = (cc & 8) | ((cc & 7) ^ (nl & 7));
      bf16x8 ap = *(const bf16x8*)(Pb + nl*128 + pch*8);
      #pragma unroll
      for (int j = 0; j < 4; ++j) {
        bf16x8 bv = *(const bf16x8*)(Vs + (j*16 + lr) * LDV + ks*32 + lg*8);
        opv[j] = __builtin_amdgcn_mfma_f32_16x16x32_bf16(ap, bv, opv[j], 0, 0, 0);
      }
    }
    __syncthreads();
  }
  #pragma unroll
  for (int j = 0; j < 4; ++j) {
    int gc = h * 64 + j*16 + lr;
    #pragma unroll
    for (int r = 0; r < 4; ++r) {
      int gr = b * NN + rowbase + w*16 + lg*4 + r;
      obh[(size_t)gr * DIM + gc] = f2bf(opv[j][r]);
    }
  }
}

// ---------- proj GEMM (bf16 MFMA) + bias -> fp32 out ----------
__global__ __launch_bounds__(256) void proj_gemm(
    const ushort* __restrict__ obh, const ushort* __restrict__ pwb,
    const float* __restrict__ pb, float* __restrict__ out)
{
  __shared__ ushort As[128 * LDK];
  __shared__ ushort Bs[128 * LDK];
  const int t = threadIdx.x, l = t & 63, w = t >> 6;
  const int bx = blockIdx.x, by = blockIdx.y;
  const int rowbase = by * 128, colbase = bx * 128;
  const int wr = w >> 1, wc = w & 1, lr = l & 15, lg = l >> 4;
  f32x4 acc[4][4] = {};
  for (int kc = 0; kc < DIM; kc += 64) {
    #pragma unroll
    for (int i = 0; i < 4; ++i) {
      int c = t + 256 * i;
      int r = c >> 3, k16 = c & 7;
      *(uint4*)(As + r * LDK + k16 * 8) =
          *(const uint4*)(obh + (size_t)(rowbase + r) * DIM + kc + k16 * 8);
      *(uint4*)(Bs + r * LDK + k16 * 8) =
          *(const uint4*)(pwb + (size_t)(colbase + r) * DIM + kc + k16 * 8);
    }
    __syncthreads();
    #pragma unroll
    for (int ks = 0; ks < 2; ++ks) {
      bf16x8 af[4], bg[4];
      #pragma unroll
      for (int i = 0; i < 4; ++i)
        af[i] = *(const bf16x8*)(As + (wr*64 + i*16 + lr) * LDK + ks*32 + lg*8);
      #pragma unroll
      for (int j = 0; j < 4; ++j)
        bg[j] = *(const bf16x8*)(Bs + (wc*64 + j*16 + lr) * LDK + ks*32 + lg*8);
      #pragma unroll
      for (int i = 0; i < 4; ++i)
        #pragma unroll
        for (int j = 0; j < 4; ++j)
          acc[i][j] = __builtin_amdgcn_mfma_f32_16x16x32_bf16(af[i], bg[j], acc[i][j], 0, 0, 0);
    }
    __syncthreads();
  }
  #pragma unroll
  for (int i = 0; i < 4; ++i) {
    #pragma unroll
    for (int r = 0; r < 4; ++r) {
      int row = rowbase + wr*64 + i*16 + lg*4 + r;
      #pragma unroll
      for (int j = 0; j < 4; ++j) {
        int col = colbase + wc*64 + j*16 + lr;
        out[(size_t)row * DIM + col] = acc[i][j][r] + pb[col];
      }
    }
  }
}

extern "C" void kernel_launch(void* const* d_in, const int* in_sizes, int n_in,
                              void* d_out, int out_size, void* d_ws, size_t ws_size,
                              hipStream_t stream) {
  const float* x      = (const float*)d_in[0];
  const float* qkv_w  = (const float*)d_in[1];
  const float* ln_w   = (const float*)d_in[2];
  const float* ln_b   = (const float*)d_in[3];
  const float* proj_w = (const float*)d_in[4];
  const float* proj_b = (const float*)d_in[5];
  float* out      = (float*)d_out;
  float* attn_out = out + OUT0_ELEMS;

  char* ws = (char*)d_ws;
  double* hsum = (double*)ws;                                 // 128 B used
  ushort* wb   = (ushort*)(ws + 256);                         // 2304*768
  ushort* pwb  = wb  + (size_t)2304 * 768;                    // 768*768
  ushort* xb   = pwb + (size_t)768 * 768;                     // 4096*768
  ushort* q2b  = xb  + (size_t)4096 * 768;                    // B*H*N*64
  ushort* k2b  = q2b + ((size_t)BB * HEADS * NN << 6);
  ushort* vt   = k2b + ((size_t)BB * HEADS * NN << 6);
  ushort* obh  = vt  + ((size_t)BB * HEADS * NN << 6);        // 4096*768

  hipMemsetAsync(hsum, 0, 128, stream);
  cvt3_kernel<<<dim3(2688), 256, 0, stream>>>(qkv_w, wb, 221184,
                                              proj_w, pwb, 73728,
                                              x, xb, 393216);
  qkv_gemm    <<<dim3(18, 32),        256, 0, stream>>>(xb, wb, q2b, k2b, vt);
  stats_kernel<<<dim3(2, HEADS, BB),  256, 0, stream>>>(q2b, k2b, hsum);
  norm_pv     <<<dim3(8, HEADS, BB),  256, 0, stream>>>(q2b, k2b, vt, ln_w, ln_b, hsum,
                                                        attn_out, obh);
  proj_gemm   <<<dim3(6, 32),         256, 0, stream>>>(obh, pwb, proj_b, out);
}